// Round 3
// baseline (429.084 us; speedup 1.0000x reference)
//
#include <hip/hip_runtime.h>

typedef short v8s __attribute__((ext_vector_type(8)));
typedef float v4f __attribute__((ext_vector_type(4)));
typedef float v32f __attribute__((ext_vector_type(32)));

__device__ __forceinline__ unsigned short f2bf(float f){
  unsigned u = __builtin_bit_cast(unsigned, f);
  return (unsigned short)((u + 0x7fffu + ((u>>16)&1u)) >> 16);
}
__device__ __forceinline__ float bf2f(unsigned short s){
  return __builtin_bit_cast(float, ((unsigned)s) << 16);
}

// -------- conv1x1 as MFMA GEMM, both tensors in one launch.
// S[tb][o][hw] = sum_k W[o][k] X[tb][k][hw] + bias[o], S staged in d_out (bf16).
// grid 4096 (2 tensors x 2048 n-tiles of 64), block 512 (8 waves, m-stripes of 48)
__global__ __launch_bounds__(512) void k_conv1x1(
    const float* __restrict__ hsi, const float* __restrict__ lidar,
    const unsigned short* __restrict__ Wbf, const float* __restrict__ hqb,
    const float* __restrict__ lkb, unsigned short* __restrict__ S)
{
  const int bx   = blockIdx.x;
  const int tens = bx >> 11;
  const int nt   = bx & 2047;
  const int b    = nt >> 8;
  const int hw0  = (nt & 255) << 6;
  const float* X = (tens ? lidar : hsi) + ((size_t)b * 192) * 16384 + hw0;
  const unsigned short* Wb = Wbf + tens * 73728;
  const float* bias = tens ? lkb : hqb;
  unsigned short* sb = S + ((size_t)(tens*8 + b) * 384) * 16384 + hw0;

  __shared__ unsigned short Xt[64][200];   // transposed bf16 X tile, padded

  // stage: thread t handles n = t&63, ko = (t>>6) + 8j  (24 k-octets total)
  {
    const int tn  = threadIdx.x & 63;
    const int kob = threadIdx.x >> 6;     // 0..7
    #pragma unroll
    for (int j = 0; j < 3; ++j){
      const int ko = kob + 8*j;
      const float* xp = X + (size_t)(ko*8) * 16384 + tn;
      v8s t;
      #pragma unroll
      for (int jj = 0; jj < 8; ++jj)
        t[jj] = (short)f2bf(xp[(size_t)jj * 16384]);
      *(v8s*)&Xt[tn][ko*8] = t;
    }
  }
  __syncthreads();

  const int lane = threadIdx.x & 63;
  const int wid  = threadIdx.x >> 6;      // 0..7
  const int l15  = lane & 15;
  const int g    = lane >> 4;
  const int mstripe = wid * 48;

  v4f acc[3][4];
  #pragma unroll
  for (int i=0;i<3;i++)
    #pragma unroll
    for (int j=0;j<4;j++)
      acc[i][j] = (v4f){0.f,0.f,0.f,0.f};

  #pragma unroll
  for (int ks=0; ks<6; ++ks){
    const int k0 = ks*32;
    v8s af[3];
    #pragma unroll
    for (int mi=0; mi<3; ++mi)
      af[mi] = *(const v8s*)(Wb + (size_t)(mstripe + mi*16 + l15)*192 + k0 + 8*g);
    #pragma unroll
    for (int ni=0; ni<4; ++ni){
      const v8s bfr = *(const v8s*)&Xt[ni*16 + l15][k0 + 8*g];
      #pragma unroll
      for (int mi=0; mi<3; ++mi)
        acc[mi][ni] = __builtin_amdgcn_mfma_f32_16x16x32_bf16(af[mi], bfr, acc[mi][ni], 0, 0, 0);
    }
  }

  #pragma unroll
  for (int mi=0; mi<3; ++mi){
    #pragma unroll
    for (int r=0; r<4; ++r){
      const int c = mstripe + mi*16 + 4*g + r;
      const float bs = bias[c];
      #pragma unroll
      for (int ni=0; ni<4; ++ni)
        sb[(size_t)c*16384 + ni*16 + l15] = f2bf(acc[mi][ni][r] + bs);
    }
  }
}

// -------- depthwise 3x3 SAME, both tensors. one thread = 8 outputs along w.
// grid 49152, block 256. idx = (bc*128 + h)*16 + w8, bc in [0,6144)
__global__ __launch_bounds__(256) void k_dw(
    const unsigned short* __restrict__ S, const float* __restrict__ hdw,
    const float* __restrict__ ldw, const float* __restrict__ hdb,
    const float* __restrict__ ldb, unsigned short* __restrict__ O)
{
  const int idx = blockIdx.x*256 + threadIdx.x;
  const int w8 = idx & 15;
  const int h  = (idx >> 4) & 127;
  const int bc = idx >> 11;
  const int c  = bc % 384;
  const int tens = (bc >= 3072);
  const unsigned short* in = S + (size_t)bc*16384;

  float r[3][10];
  #pragma unroll
  for (int dy=0; dy<3; ++dy){
    const int hh = h + dy - 1;
    if (hh >= 0 && hh < 128){
      const unsigned short* row = in + hh*128 + w8*8;
      const v8s m = *(const v8s*)row;
      #pragma unroll
      for (int i=0;i<8;++i) r[dy][i+1] = bf2f((unsigned short)m[i]);
      r[dy][0] = (w8 > 0)  ? bf2f(row[-1]) : 0.f;
      r[dy][9] = (w8 < 15) ? bf2f(row[8])  : 0.f;
    } else {
      #pragma unroll
      for (int i=0;i<10;++i) r[dy][i] = 0.f;
    }
  }
  const float* wp = (tens ? ldw : hdw) + c*9;
  const float k00=wp[0],k01=wp[1],k02=wp[2],k10=wp[3],k11=wp[4],k12=wp[5],k20=wp[6],k21=wp[7],k22=wp[8];
  const float bs = (tens ? ldb : hdb)[c];
  v8s out;
  #pragma unroll
  for (int j=0;j<8;++j){
    float a = bs
      + r[0][j]*k00 + r[0][j+1]*k01 + r[0][j+2]*k02
      + r[1][j]*k10 + r[1][j+1]*k11 + r[1][j+2]*k12
      + r[2][j]*k20 + r[2][j+1]*k21 + r[2][j+2]*k22;
    out[j] = (short)f2bf(a);
  }
  *(v8s*)(O + (size_t)bc*16384 + h*128 + w8*8) = out;
}

// -------- QK^T partials + row sumsq via Gram MFMAs.
// grid (48, 16), block 256 (4 waves, 256 s each). P: [48][64][1088]
__global__ __launch_bounds__(256) void k_qk(
    const unsigned short* __restrict__ Q, const unsigned short* __restrict__ K,
    float* __restrict__ P)
{
  const int bh = blockIdx.x, split = blockIdx.y;
  const int lane = threadIdx.x & 63, wid = threadIdx.x >> 6;
  const int l15 = lane & 15, g = lane >> 4;
  const int b = bh/6, hd = bh%6;
  const unsigned short* qb = Q + ((size_t)b*384 + hd*32)*16384;
  const unsigned short* kb = K + ((size_t)b*384 + hd*32)*16384;
  const int s0 = (split*4 + wid)*256;

  v4f aqk[2][2], aqq[2], akk[2];
  #pragma unroll
  for (int i=0;i<2;i++){
    aqq[i] = (v4f){0.f,0.f,0.f,0.f};
    akk[i] = (v4f){0.f,0.f,0.f,0.f};
    #pragma unroll
    for (int j=0;j<2;j++) aqk[i][j] = (v4f){0.f,0.f,0.f,0.f};
  }

  #pragma unroll
  for (int ks=0; ks<8; ++ks){
    const int s = s0 + ks*32 + 8*g;
    v8s qf[2], kf[2];
    #pragma unroll
    for (int mi=0;mi<2;++mi) qf[mi] = *(const v8s*)(qb + (size_t)(mi*16 + l15)*16384 + s);
    #pragma unroll
    for (int ni=0;ni<2;++ni) kf[ni] = *(const v8s*)(kb + (size_t)(ni*16 + l15)*16384 + s);
    #pragma unroll
    for (int mi=0;mi<2;++mi)
      #pragma unroll
      for (int ni=0;ni<2;++ni)
        aqk[mi][ni] = __builtin_amdgcn_mfma_f32_16x16x32_bf16(qf[mi], kf[ni], aqk[mi][ni],0,0,0);
    #pragma unroll
    for (int mi=0;mi<2;++mi){
      aqq[mi] = __builtin_amdgcn_mfma_f32_16x16x32_bf16(qf[mi], qf[mi], aqq[mi],0,0,0);
      akk[mi] = __builtin_amdgcn_mfma_f32_16x16x32_bf16(kf[mi], kf[mi], akk[mi],0,0,0);
    }
  }
  float* slot = P + ((size_t)bh*64 + split*4 + wid)*1088;
  #pragma unroll
  for (int mi=0;mi<2;++mi)
    #pragma unroll
    for (int ni=0;ni<2;++ni)
      #pragma unroll
      for (int r=0;r<4;++r)
        slot[(mi*16 + 4*g + r)*32 + ni*16 + l15] = aqk[mi][ni][r];
  #pragma unroll
  for (int mi=0;mi<2;++mi)
    #pragma unroll
    for (int r=0;r<4;++r)
      if (l15 == 4*g + r){
        slot[1024 + mi*16 + l15] = aqq[mi][r];
        slot[1056 + mi*16 + l15] = akk[mi][r];
      }
}

// -------- reduce partials, l2-normalize, temperature, softmax, fold +I -> A[48][32][32]
__global__ __launch_bounds__(256) void k_sm(
    const float* __restrict__ P, const float* __restrict__ temp, float* __restrict__ A)
{
  __shared__ float red[1088];
  const int bh = blockIdx.x, t = threadIdx.x;
  const float* base = P + (size_t)bh*64*1088;
  for (int i=t; i<1088; i+=256){
    float s = 0.f;
    for (int sl=0; sl<64; ++sl) s += base[(size_t)sl*1088 + i];
    red[i] = s;
  }
  __syncthreads();
  const int c = t >> 3, dq = t & 7;
  const float qn = fmaxf(sqrtf(red[1024+c]), 1e-12f);
  const float tp = temp[bh % 6];
  float v[4];
  #pragma unroll
  for (int r=0;r<4;++r){
    const int d = dq*4 + r;
    const float kn = fmaxf(sqrtf(red[1056+d]), 1e-12f);
    v[r] = red[c*32+d] / (qn*kn) * tp;
  }
  float mx = fmaxf(fmaxf(v[0],v[1]), fmaxf(v[2],v[3]));
  mx = fmaxf(mx, __shfl_xor(mx,1));
  mx = fmaxf(mx, __shfl_xor(mx,2));
  mx = fmaxf(mx, __shfl_xor(mx,4));
  float e[4]; float sum = 0.f;
  #pragma unroll
  for (int r=0;r<4;++r){ e[r] = __expf(v[r]-mx); sum += e[r]; }
  sum += __shfl_xor(sum,1); sum += __shfl_xor(sum,2); sum += __shfl_xor(sum,4);
  const float inv = 1.f/sum;
  #pragma unroll
  for (int r=0;r<4;++r){
    const int d = dq*4 + r;
    A[(size_t)bh*1024 + c*32 + d] = e[r]*inv + ((c == d) ? 1.f : 0.f);
  }
}

// -------- out = (A+I)@V + x, one tensor per block. grid (96, 32), block 256, 2 cols/thread
// V kept in two ext-vector registers (never dynamically indexed -> guaranteed VGPRs)
#define R32(M) M(0) M(1) M(2) M(3) M(4) M(5) M(6) M(7) M(8) M(9) M(10) M(11) M(12) M(13) M(14) M(15) \
               M(16) M(17) M(18) M(19) M(20) M(21) M(22) M(23) M(24) M(25) M(26) M(27) M(28) M(29) M(30) M(31)

__global__ __launch_bounds__(256) void k_out(
    const float* __restrict__ A, const unsigned short* __restrict__ QVh,
    const unsigned short* __restrict__ KVl, const float* __restrict__ hsi,
    const float* __restrict__ lidar, float* __restrict__ outh, float* __restrict__ outl)
{
  const int tens = blockIdx.x & 1;
  const int bh = blockIdx.x >> 1;
  const int s = (blockIdx.y*256 + threadIdx.x)*2;
  const int b = bh/6, hd = bh%6;
  const float* Ab = A + (size_t)bh*1024;
  const unsigned short* V = (tens ? KVl : QVh) + ((size_t)b*384 + 192 + hd*32)*16384 + s;
  const float* X = (tens ? lidar : hsi) + ((size_t)b*192 + hd*32)*16384 + s;
  float* O = (tens ? outl : outh) + ((size_t)b*192 + hd*32)*16384 + s;

  v32f vx, vy;
#define LD_V(dd) { const unsigned u = *(const unsigned*)(V + (size_t)(dd)*16384); \
                   vx[dd] = bf2f((unsigned short)u); vy[dd] = bf2f((unsigned short)(u >> 16)); }
  R32(LD_V)
#undef LD_V

  for (int c=0; c<32; ++c){
    const float* Arow = Ab + c*32;
    const float2 x = *(const float2*)(X + (size_t)c*16384);
    float ax = x.x, ay = x.y;
#define FMA_D(dd) { const float a = Arow[dd]; ax += a*vx[dd]; ay += a*vy[dd]; }
    R32(FMA_D)
#undef FMA_D
    float2 o; o.x = ax; o.y = ay;
    *(float2*)(O + (size_t)c*16384) = o;
  }
}

// -------- convert both 1x1 weights to bf16 once per call
__global__ __launch_bounds__(256) void k_wcvt(
    const float* __restrict__ a, const float* __restrict__ b, unsigned short* __restrict__ o)
{
  const int i = blockIdx.x*256 + threadIdx.x;
  if (i < 73728) o[i] = f2bf(a[i]);
  else if (i < 147456) o[i] = f2bf(b[i - 73728]);
}

extern "C" void kernel_launch(void* const* d_in, const int* in_sizes, int n_in,
                              void* d_out, int out_size, void* d_ws, size_t ws_size,
                              hipStream_t stream) {
  const float* hsi   = (const float*)d_in[0];
  const float* lidar = (const float*)d_in[1];
  const float* hqw   = (const float*)d_in[2];
  const float* hqb   = (const float*)d_in[3];
  const float* lkw   = (const float*)d_in[4];
  const float* lkb   = (const float*)d_in[5];
  const float* hdw   = (const float*)d_in[6];
  const float* hdb   = (const float*)d_in[7];
  const float* ldw   = (const float*)d_in[8];
  const float* ldb   = (const float*)d_in[9];
  const float* temp  = (const float*)d_in[10];

  char* ws = (char*)d_ws;
  unsigned short* QVh = (unsigned short*)(ws);                 // 100663296 B
  unsigned short* KVl = (unsigned short*)(ws + 100663296);     // 100663296 B
  unsigned short* Wbf = (unsigned short*)(ws + 201326592);     // 294912 B
  float* P            = (float*)(ws + 201621504);              // 13369344 B
  float* A            = (float*)(ws + 214990848);              // 196608 B

  float* outh = (float*)d_out;
  float* outl = outh + 25165824;
  // stage conv1x1 output (both tensors, bf16) inside d_out: exactly 201326592 B
  unsigned short* S0 = (unsigned short*)d_out;

  k_wcvt<<<576, 256, 0, stream>>>(hqw, lkw, Wbf);
  k_conv1x1<<<4096, 512, 0, stream>>>(hsi, lidar, Wbf, hqb, lkb, S0);
  k_dw<<<49152, 256, 0, stream>>>(S0, hdw, ldw, hdb, ldb, QVh);
  k_qk<<<dim3(48, 16), 256, 0, stream>>>(QVh, KVl, P);
  k_sm<<<48, 256, 0, stream>>>(P, temp, A);
  k_out<<<dim3(96, 32), 256, 0, stream>>>(A, QVh, KVl, hsi, lidar, outh, outl);
}

// Round 4
// 383.165 us; speedup vs baseline: 1.1198x; 1.1198x over previous
//
#include <hip/hip_runtime.h>

typedef short v8s __attribute__((ext_vector_type(8)));
typedef float v4f __attribute__((ext_vector_type(4)));
typedef float v32f __attribute__((ext_vector_type(32)));

__device__ __forceinline__ unsigned short f2bf(float f){
  unsigned u = __builtin_bit_cast(unsigned, f);
  return (unsigned short)((u + 0x7fffu + ((u>>16)&1u)) >> 16);
}
__device__ __forceinline__ float bf2f(unsigned short s){
  return __builtin_bit_cast(float, ((unsigned)s) << 16);
}

// -------- conv1x1 as MFMA GEMM, both tensors in one launch.
// S[tb][o][hw] = sum_k W[o][k] X[tb][k][hw] + bias[o], S staged in d_out (bf16).
// grid 4096 (2 tensors x 2048 n-tiles of 64), block 512 (8 waves, m-stripes of 48).
// Staging: float4 loads (6 in flight/thread), b32 LDS writes.
// W pre-swizzled to fragment order: Wfrag[tens][wid][ks][mi][lane][8]
__global__ __launch_bounds__(512) void k_conv1x1(
    const float* __restrict__ hsi, const float* __restrict__ lidar,
    const unsigned short* __restrict__ Wfrag, const float* __restrict__ hqb,
    const float* __restrict__ lkb, unsigned short* __restrict__ S)
{
  const int bx   = blockIdx.x;
  const int tens = bx >> 11;
  const int nt   = bx & 2047;
  const int b    = nt >> 8;
  const int hw0  = (nt & 255) << 6;
  const float* X = (tens ? lidar : hsi) + ((size_t)b * 192) * 16384 + hw0;
  const float* bias = tens ? lkb : hqb;
  unsigned short* sb = S + ((size_t)(tens*8 + b) * 384) * 16384 + hw0;

  __shared__ unsigned short Xt[64][200];   // transposed bf16 X tile, padded

  // stage: thread t -> cols c4..c4+3, rows {2*krow, 2*krow+1} + 64j
  {
    const int c4   = (threadIdx.x & 15) * 4;
    const int krow = threadIdx.x >> 4;     // 0..31
    const float* xb2 = X + c4;
    float4 f[6];
    #pragma unroll
    for (int j = 0; j < 3; ++j){
      const int k = krow*2 + j*64;
      f[2*j]   = *(const float4*)(xb2 + (size_t)k * 16384);
      f[2*j+1] = *(const float4*)(xb2 + (size_t)(k+1) * 16384);
    }
    #pragma unroll
    for (int j = 0; j < 3; ++j){
      const int k = krow*2 + j*64;
      #pragma unroll
      for (int i2 = 0; i2 < 4; ++i2){
        const unsigned lo = f2bf(((const float*)&f[2*j])[i2]);
        const unsigned hi = f2bf(((const float*)&f[2*j+1])[i2]);
        *(unsigned*)&Xt[c4 + i2][k] = lo | (hi << 16);
      }
    }
  }
  __syncthreads();

  const int lane = threadIdx.x & 63;
  const int wid  = threadIdx.x >> 6;      // 0..7
  const int l15  = lane & 15;
  const int g    = lane >> 4;
  const int mstripe = wid * 48;
  // fragment-ordered W base for this wave
  const unsigned short* wb = Wfrag + ((size_t)(tens*8 + wid) * 18) * 512 + (lane << 3);

  v4f acc[3][4];
  #pragma unroll
  for (int i=0;i<3;i++)
    #pragma unroll
    for (int j=0;j<4;j++)
      acc[i][j] = (v4f){0.f,0.f,0.f,0.f};

  #pragma unroll
  for (int ks=0; ks<6; ++ks){
    const int k0 = ks*32;
    v8s af[3];
    #pragma unroll
    for (int mi=0; mi<3; ++mi)
      af[mi] = *(const v8s*)(wb + (size_t)(ks*3 + mi) * 512);
    #pragma unroll
    for (int ni=0; ni<4; ++ni){
      const v8s bfr = *(const v8s*)&Xt[ni*16 + l15][k0 + 8*g];
      #pragma unroll
      for (int mi=0; mi<3; ++mi)
        acc[mi][ni] = __builtin_amdgcn_mfma_f32_16x16x32_bf16(af[mi], bfr, acc[mi][ni], 0, 0, 0);
    }
  }

  #pragma unroll
  for (int mi=0; mi<3; ++mi){
    #pragma unroll
    for (int r=0; r<4; ++r){
      const int c = mstripe + mi*16 + 4*g + r;
      const float bs = bias[c];
      #pragma unroll
      for (int ni=0; ni<4; ++ni)
        sb[(size_t)c*16384 + ni*16 + l15] = f2bf(acc[mi][ni][r] + bs);
    }
  }
}

// -------- depthwise 3x3 SAME, both tensors. one thread = 8 outputs along w.
// grid 49152, block 256. idx = (bc*128 + h)*16 + w8, bc in [0,6144)
__global__ __launch_bounds__(256) void k_dw(
    const unsigned short* __restrict__ S, const float* __restrict__ hdw,
    const float* __restrict__ ldw, const float* __restrict__ hdb,
    const float* __restrict__ ldb, unsigned short* __restrict__ O)
{
  const int idx = blockIdx.x*256 + threadIdx.x;
  const int w8 = idx & 15;
  const int h  = (idx >> 4) & 127;
  const int bc = idx >> 11;
  const int c  = bc % 384;
  const int tens = (bc >= 3072);
  const unsigned short* in = S + (size_t)bc*16384;

  float r[3][10];
  #pragma unroll
  for (int dy=0; dy<3; ++dy){
    const int hh = h + dy - 1;
    if (hh >= 0 && hh < 128){
      const unsigned short* row = in + hh*128 + w8*8;
      const v8s m = *(const v8s*)row;
      #pragma unroll
      for (int i=0;i<8;++i) r[dy][i+1] = bf2f((unsigned short)m[i]);
      r[dy][0] = (w8 > 0)  ? bf2f(row[-1]) : 0.f;
      r[dy][9] = (w8 < 15) ? bf2f(row[8])  : 0.f;
    } else {
      #pragma unroll
      for (int i=0;i<10;++i) r[dy][i] = 0.f;
    }
  }
  const float* wp = (tens ? ldw : hdw) + c*9;
  const float k00=wp[0],k01=wp[1],k02=wp[2],k10=wp[3],k11=wp[4],k12=wp[5],k20=wp[6],k21=wp[7],k22=wp[8];
  const float bs = (tens ? ldb : hdb)[c];
  v8s out;
  #pragma unroll
  for (int j=0;j<8;++j){
    float a = bs
      + r[0][j]*k00 + r[0][j+1]*k01 + r[0][j+2]*k02
      + r[1][j]*k10 + r[1][j+1]*k11 + r[1][j+2]*k12
      + r[2][j]*k20 + r[2][j+1]*k21 + r[2][j+2]*k22;
    out[j] = (short)f2bf(a);
  }
  *(v8s*)(O + (size_t)bc*16384 + h*128 + w8*8) = out;
}

// -------- QK^T partials + row sumsq via Gram MFMAs.
// grid (48, 16), block 256 (4 waves, 256 s each). P: [48][64][1088]
__global__ __launch_bounds__(256) void k_qk(
    const unsigned short* __restrict__ Q, const unsigned short* __restrict__ K,
    float* __restrict__ P)
{
  const int bh = blockIdx.x, split = blockIdx.y;
  const int lane = threadIdx.x & 63, wid = threadIdx.x >> 6;
  const int l15 = lane & 15, g = lane >> 4;
  const int b = bh/6, hd = bh%6;
  const unsigned short* qb = Q + ((size_t)b*384 + hd*32)*16384;
  const unsigned short* kb = K + ((size_t)b*384 + hd*32)*16384;
  const int s0 = (split*4 + wid)*256;

  v4f aqk[2][2], aqq[2], akk[2];
  #pragma unroll
  for (int i=0;i<2;i++){
    aqq[i] = (v4f){0.f,0.f,0.f,0.f};
    akk[i] = (v4f){0.f,0.f,0.f,0.f};
    #pragma unroll
    for (int j=0;j<2;j++) aqk[i][j] = (v4f){0.f,0.f,0.f,0.f};
  }

  #pragma unroll
  for (int ks=0; ks<8; ++ks){
    const int s = s0 + ks*32 + 8*g;
    v8s qf[2], kf[2];
    #pragma unroll
    for (int mi=0;mi<2;++mi) qf[mi] = *(const v8s*)(qb + (size_t)(mi*16 + l15)*16384 + s);
    #pragma unroll
    for (int ni=0;ni<2;++ni) kf[ni] = *(const v8s*)(kb + (size_t)(ni*16 + l15)*16384 + s);
    #pragma unroll
    for (int mi=0;mi<2;++mi)
      #pragma unroll
      for (int ni=0;ni<2;++ni)
        aqk[mi][ni] = __builtin_amdgcn_mfma_f32_16x16x32_bf16(qf[mi], kf[ni], aqk[mi][ni],0,0,0);
    #pragma unroll
    for (int mi=0;mi<2;++mi){
      aqq[mi] = __builtin_amdgcn_mfma_f32_16x16x32_bf16(qf[mi], qf[mi], aqq[mi],0,0,0);
      akk[mi] = __builtin_amdgcn_mfma_f32_16x16x32_bf16(kf[mi], kf[mi], akk[mi],0,0,0);
    }
  }
  float* slot = P + ((size_t)bh*64 + split*4 + wid)*1088;
  #pragma unroll
  for (int mi=0;mi<2;++mi)
    #pragma unroll
    for (int ni=0;ni<2;++ni)
      #pragma unroll
      for (int r=0;r<4;++r)
        slot[(mi*16 + 4*g + r)*32 + ni*16 + l15] = aqk[mi][ni][r];
  #pragma unroll
  for (int mi=0;mi<2;++mi)
    #pragma unroll
    for (int r=0;r<4;++r)
      if (l15 == 4*g + r){
        slot[1024 + mi*16 + l15] = aqq[mi][r];
        slot[1056 + mi*16 + l15] = akk[mi][r];
      }
}

// -------- reduce partials, l2-normalize, temperature, softmax, fold +I -> A[48][32][32]
__global__ __launch_bounds__(256) void k_sm(
    const float* __restrict__ P, const float* __restrict__ temp, float* __restrict__ A)
{
  __shared__ float red[1088];
  const int bh = blockIdx.x, t = threadIdx.x;
  const float* base = P + (size_t)bh*64*1088;
  for (int i=t; i<1088; i+=256){
    float s = 0.f;
    for (int sl=0; sl<64; ++sl) s += base[(size_t)sl*1088 + i];
    red[i] = s;
  }
  __syncthreads();
  const int c = t >> 3, dq = t & 7;
  const float qn = fmaxf(sqrtf(red[1024+c]), 1e-12f);
  const float tp = temp[bh % 6];
  float v[4];
  #pragma unroll
  for (int r=0;r<4;++r){
    const int d = dq*4 + r;
    const float kn = fmaxf(sqrtf(red[1056+d]), 1e-12f);
    v[r] = red[c*32+d] / (qn*kn) * tp;
  }
  float mx = fmaxf(fmaxf(v[0],v[1]), fmaxf(v[2],v[3]));
  mx = fmaxf(mx, __shfl_xor(mx,1));
  mx = fmaxf(mx, __shfl_xor(mx,2));
  mx = fmaxf(mx, __shfl_xor(mx,4));
  float e[4]; float sum = 0.f;
  #pragma unroll
  for (int r=0;r<4;++r){ e[r] = __expf(v[r]-mx); sum += e[r]; }
  sum += __shfl_xor(sum,1); sum += __shfl_xor(sum,2); sum += __shfl_xor(sum,4);
  const float inv = 1.f/sum;
  #pragma unroll
  for (int r=0;r<4;++r){
    const int d = dq*4 + r;
    A[(size_t)bh*1024 + c*32 + d] = e[r]*inv + ((c == d) ? 1.f : 0.f);
  }
}

// -------- out = (A+I)@V + x, one tensor per block. grid (96, 32), block 256, 2 cols/thread
// V kept in two ext-vector registers (never dynamically indexed -> guaranteed VGPRs)
#define R32(M) M(0) M(1) M(2) M(3) M(4) M(5) M(6) M(7) M(8) M(9) M(10) M(11) M(12) M(13) M(14) M(15) \
               M(16) M(17) M(18) M(19) M(20) M(21) M(22) M(23) M(24) M(25) M(26) M(27) M(28) M(29) M(30) M(31)

__global__ __launch_bounds__(256) void k_out(
    const float* __restrict__ A, const unsigned short* __restrict__ QVh,
    const unsigned short* __restrict__ KVl, const float* __restrict__ hsi,
    const float* __restrict__ lidar, float* __restrict__ outh, float* __restrict__ outl)
{
  const int tens = blockIdx.x & 1;
  const int bh = blockIdx.x >> 1;
  const int s = (blockIdx.y*256 + threadIdx.x)*2;
  const int b = bh/6, hd = bh%6;
  const float* Ab = A + (size_t)bh*1024;
  const unsigned short* V = (tens ? KVl : QVh) + ((size_t)b*384 + 192 + hd*32)*16384 + s;
  const float* X = (tens ? lidar : hsi) + ((size_t)b*192 + hd*32)*16384 + s;
  float* O = (tens ? outl : outh) + ((size_t)b*192 + hd*32)*16384 + s;

  v32f vx, vy;
#define LD_V(dd) { const unsigned u = *(const unsigned*)(V + (size_t)(dd)*16384); \
                   vx[dd] = bf2f((unsigned short)u); vy[dd] = bf2f((unsigned short)(u >> 16)); }
  R32(LD_V)
#undef LD_V

  for (int c=0; c<32; ++c){
    const float* Arow = Ab + c*32;
    const float2 x = *(const float2*)(X + (size_t)c*16384);
    float ax = x.x, ay = x.y;
#define FMA_D(dd) { const float a = Arow[dd]; ax += a*vx[dd]; ay += a*vy[dd]; }
    R32(FMA_D)
#undef FMA_D
    float2 o; o.x = ax; o.y = ay;
    *(float2*)(O + (size_t)c*16384) = o;
  }
}

// -------- convert both 1x1 weights to bf16 in MFMA fragment order:
// Wfrag[tens][wid(8)][ks(6)][mi(3)][lane(64)][8]
__global__ __launch_bounds__(256) void k_wcvt(
    const float* __restrict__ a, const float* __restrict__ b, unsigned short* __restrict__ o)
{
  const int i = blockIdx.x*256 + threadIdx.x;
  if (i >= 147456) return;
  const int jj = i & 7;
  const int l  = (i >> 3) & 63;
  const int rest = i >> 9;          // ((tens*8+wid)*6+ks)*3+mi, 0..287
  const int mi = rest % 3;
  const int ks = (rest / 3) % 6;
  const int q  = rest / 18;         // tens*8 + wid
  const int wid = q & 7, tens = q >> 3;
  const int row = wid*48 + mi*16 + (l & 15);
  const int col = ks*32 + (l >> 4)*8 + jj;
  const float* src = tens ? b : a;
  o[i] = f2bf(src[row*192 + col]);
}

extern "C" void kernel_launch(void* const* d_in, const int* in_sizes, int n_in,
                              void* d_out, int out_size, void* d_ws, size_t ws_size,
                              hipStream_t stream) {
  const float* hsi   = (const float*)d_in[0];
  const float* lidar = (const float*)d_in[1];
  const float* hqw   = (const float*)d_in[2];
  const float* hqb   = (const float*)d_in[3];
  const float* lkw   = (const float*)d_in[4];
  const float* lkb   = (const float*)d_in[5];
  const float* hdw   = (const float*)d_in[6];
  const float* hdb   = (const float*)d_in[7];
  const float* ldw   = (const float*)d_in[8];
  const float* ldb   = (const float*)d_in[9];
  const float* temp  = (const float*)d_in[10];

  char* ws = (char*)d_ws;
  unsigned short* QVh = (unsigned short*)(ws);                 // 100663296 B
  unsigned short* KVl = (unsigned short*)(ws + 100663296);     // 100663296 B
  unsigned short* Wbf = (unsigned short*)(ws + 201326592);     // 294912 B
  float* P            = (float*)(ws + 201621504);              // 13369344 B
  float* A            = (float*)(ws + 214990848);              // 196608 B

  float* outh = (float*)d_out;
  float* outl = outh + 25165824;
  // stage conv1x1 output (both tensors, bf16) inside d_out: exactly 201326592 B
  unsigned short* S0 = (unsigned short*)d_out;

  k_wcvt<<<576, 256, 0, stream>>>(hqw, lkw, Wbf);
  k_conv1x1<<<4096, 512, 0, stream>>>(hsi, lidar, Wbf, hqb, lkb, S0);
  k_dw<<<49152, 256, 0, stream>>>(S0, hdw, ldw, hdb, ldb, QVh);
  k_qk<<<dim3(48, 16), 256, 0, stream>>>(QVh, KVl, P);
  k_sm<<<48, 256, 0, stream>>>(P, temp, A);
  k_out<<<dim3(96, 32), 256, 0, stream>>>(A, QVh, KVl, hsi, lidar, outh, outl);
}